// Round 15
// baseline (913.362 us; speedup 1.0000x reference)
//
#include <hip/hip_runtime.h>

#define NN 50000
#define NE 800000
#define INF 7
#define GD 16
#define LAT 64
#define HID 128

typedef unsigned short u16;
typedef __attribute__((ext_vector_type(8))) __bf16 bf16x8;
typedef __attribute__((ext_vector_type(4))) float f32x4;

__device__ __forceinline__ float bf2f(u16 u) {
  union { unsigned int i; float f; } v; v.i = ((unsigned int)u) << 16; return v.f;
}
__device__ __forceinline__ u16 f2bf(float f) {
  union { float f; unsigned int i; } v; v.f = f;
  unsigned int x = v.i;
  return (u16)((x + 0x7fffu + ((x >> 16) & 1u)) >> 16);
}
// jax.nn.gelu approximate (tanh form) as x*sigmoid(2z) with v_rcp (r11-verified).
__device__ __forceinline__ float gelu(float x) {
  float u = x * x;
  float p = fmaf(0.044715f * u, x, x);
  float e = __expf(-1.5957691216057308f * p);
  return x * __builtin_amdgcn_rcpf(e + 1.0f);
}

// ---- consolidated weight pre-pack: 13 jobs in one dispatch.
struct PackJobs {
  const float* src[13];
  u16* dst[13];
  int K[13];
  int N[13];
  int KC[13];
};

__global__ void pack_all(PackJobs J) {
  const int j = blockIdx.y;
  const int KC = J.KC[j];
  const float* W = J.src[j];
  u16* out = J.dst[j];
  int t = blockIdx.x * blockDim.x + threadIdx.x;
  if (KC == 0) {            // gpad job
    if (t < 32) out[t] = (t < GD) ? f2bf(W[t]) : (u16)0;
    return;
  }
  const int K = J.K[j], N = J.N[j];
  const int NT = N >> 4;
  if (t >= KC * NT * 64) return;
  int l = t & 63;
  int nt = (t >> 6) % NT;
  int kc = t / (64 * NT);
  int n = nt * 16 + (l & 15);
  int kbase = kc * 32 + (l >> 4) * 8;
  ushort4 lo, hi;
  u16 v[8];
#pragma unroll
  for (int jj = 0; jj < 8; ++jj) {
    int k = kbase + jj;
    v[jj] = (k < K) ? f2bf(W[k * N + n]) : (u16)0;
  }
  lo.x = v[0]; lo.y = v[1]; lo.z = v[2]; lo.w = v[3];
  hi.x = v[4]; hi.y = v[5]; hi.z = v[6]; hi.w = v[7];
  ushort4* dst = (ushort4*)&out[(size_t)t * 8];
  dst[0] = lo; dst[1] = hi;
}

__global__ void embed_kernel(const float* __restrict__ nodes, const float* __restrict__ w,
                             const float* __restrict__ b, float* __restrict__ h,
                             u16* __restrict__ hbf) {
  int gid = blockIdx.x * blockDim.x + threadIdx.x;
  if (gid >= NN * LAT) return;
  int n = gid >> 6, j = gid & 63;
  float acc = b[j];
#pragma unroll
  for (int k = 0; k < INF; ++k)
    acc = fmaf(nodes[n * INF + k], w[k * LAT + j], acc);
  h[gid] = acc;
  hbf[gid] = f2bf(acc);
}

// ---- MFMA edge MLP, software-pipelined: ONE barrier per tile (was two).
// Double-buffered hid/easm/rcvs; iteration k: copy easm(t-G) -> phase2(t) ->
// phase1(t+G) -> barrier. ebuf write of tile T happens one iteration late
// (rows disjoint from any concurrent phase1 read; tiles partition edges and
// each tile is owned by one block). r13 numerics per output (unsorted edges,
// plain atomics). NO weight LDS staging (quarantined: r8/r9/r10).
// K layout FIRST: [s 64][r 64][g 16|pad] = 160 (KC=5)
//          else : [e 64][s 64][r 64][g 16|pad] = 224 (KC=7)
template <int KC, bool FIRST>
__launch_bounds__(256)
__global__ void edge_mfma(const u16* __restrict__ hbf, u16* __restrict__ ebuf,
                          float* __restrict__ recvbuf,
                          const int* __restrict__ snd, const int* __restrict__ rcv,
                          const u16* __restrict__ gpad,
                          const u16* __restrict__ w1p, const float* __restrict__ b1,
                          const u16* __restrict__ w2p, const float* __restrict__ b2) {
  __shared__ __align__(16) u16 hid[2][32 * 136];   // 2 x 8.7 KB
  __shared__ __align__(16) u16 easm[2][32 * 64];   // 2 x 4 KB
  __shared__ int rcvs[2][32];

  const int tid = threadIdx.x;
  const int lane = tid & 63;
  const int w = tid >> 6;
  const int l15 = lane & 15;
  const int q = lane >> 4;
  const int mr = w & 1;              // row-tile (16 rows) for both phases
  const int ntb1 = (w >> 1) * 4;     // phase-1 col-tiles (4 of 8)
  const int ntb2 = (w >> 1) * 2;     // phase-2 col-tiles (2 of 4)
  const int arow = mr * 16 + l15;
  const int NTILE = NE / 32;
  const int G = gridDim.x;

  float bb1[4], bb2[2];
#pragma unroll
  for (int i = 0; i < 4; ++i) bb1[i] = b1[(ntb1 + i) * 16 + l15];
#pragma unroll
  for (int i = 0; i < 2; ++i) bb2[i] = b2[(ntb2 + i) * 16 + l15];

  int tile = blockIdx.x;             // grid (2048) < NTILE (25000): always valid
  int s_cur = snd[tile * 32 + arow];
  int r_cur = rcv[tile * 32 + arow];
  int s_nxt = 0, r_nxt = 0;
  if (tile + G < NTILE) {
    s_nxt = snd[(tile + G) * 32 + arow];
    r_nxt = rcv[(tile + G) * 32 + arow];
  }
  if (tid < 32) rcvs[0][tid] = rcv[tile * 32 + tid];

  // ---- prologue: phase1(tile0) -> hid[0]
  {
    const int eg = tile * 32 + arow;
    const int soff = s_cur * 64;
    const int roff = r_cur * 64;
    f32x4 acc[4];
#pragma unroll
    for (int i = 0; i < 4; ++i) acc[i] = (f32x4){bb1[i], bb1[i], bb1[i], bb1[i]};
#pragma unroll
    for (int kc = 0; kc < KC; ++kc) {
      const u16* abase;
      if (FIRST) {
        abase = (kc < 2) ? &hbf[soff + kc * 32]
              : (kc < 4) ? &hbf[roff + (kc - 2) * 32]
              :            &gpad[0];
      } else {
        abase = (kc < 2) ? &ebuf[(size_t)eg * 64 + kc * 32]
              : (kc < 4) ? &hbf[soff + (kc - 2) * 32]
              : (kc < 6) ? &hbf[roff + (kc - 4) * 32]
              :            &gpad[0];
      }
      bf16x8 a = *(const bf16x8*)&abase[q * 8];
#pragma unroll
      for (int i = 0; i < 4; ++i) {
        bf16x8 b = *(const bf16x8*)&w1p[(size_t)((kc * 8 + ntb1 + i) * 64 + lane) * 8];
        acc[i] = __builtin_amdgcn_mfma_f32_16x16x32_bf16(a, b, acc[i], 0, 0, 0);
      }
    }
#pragma unroll
    for (int i = 0; i < 4; ++i) {
      const int col = (ntb1 + i) * 16 + l15;
#pragma unroll
      for (int r4 = 0; r4 < 4; ++r4) {
        const int row = mr * 16 + q * 4 + r4;
        hid[0][row * 136 + col] = f2bf(gelu(acc[i][r4]));
      }
    }
  }
  __syncthreads();

  int cur = 0;
  for (; tile < NTILE; tile += G) {
    const int tnext = tile + G;
    // ---- delayed e_out write for tile-G (easm[cur^1] complete since last barrier)
    if (tile != (int)blockIdx.x)
      ((uint4*)&ebuf[(size_t)(tile - G) * 2048])[tid] = ((const uint4*)easm[cur ^ 1])[tid];

    // ---- phase 2 on hid[cur]: out = hid @ W2 + b2; easm[cur] + atomics
    {
      f32x4 acc[2];
#pragma unroll
      for (int i = 0; i < 2; ++i) acc[i] = (f32x4){bb2[i], bb2[i], bb2[i], bb2[i]};
#pragma unroll
      for (int kc = 0; kc < 4; ++kc) {
        bf16x8 a = *(const bf16x8*)&hid[cur][arow * 136 + kc * 32 + q * 8];
#pragma unroll
        for (int i = 0; i < 2; ++i) {
          bf16x8 b = *(const bf16x8*)&w2p[(size_t)((kc * 4 + ntb2 + i) * 64 + lane) * 8];
          acc[i] = __builtin_amdgcn_mfma_f32_16x16x32_bf16(a, b, acc[i], 0, 0, 0);
        }
      }
#pragma unroll
      for (int i = 0; i < 2; ++i) {
        const int col = (ntb2 + i) * 16 + l15;
#pragma unroll
        for (int r4 = 0; r4 < 4; ++r4) {
          const int row = mr * 16 + q * 4 + r4;
          const float v = acc[i][r4];
          easm[cur][row * 64 + col] = f2bf(v);
          atomicAdd(&recvbuf[(size_t)rcvs[cur][row] * 64 + col], v);
        }
      }
    }

    // ---- phase 1 for tnext -> hid[cur^1]
    if (tnext < NTILE) {
      if (tid < 32) rcvs[cur ^ 1][tid] = rcv[tnext * 32 + tid];
      const int egn = tnext * 32 + arow;
      const int soff = s_nxt * 64;
      const int roff = r_nxt * 64;
      f32x4 acc[4];
#pragma unroll
      for (int i = 0; i < 4; ++i) acc[i] = (f32x4){bb1[i], bb1[i], bb1[i], bb1[i]};
#pragma unroll
      for (int kc = 0; kc < KC; ++kc) {
        const u16* abase;
        if (FIRST) {
          abase = (kc < 2) ? &hbf[soff + kc * 32]
                : (kc < 4) ? &hbf[roff + (kc - 2) * 32]
                :            &gpad[0];
        } else {
          abase = (kc < 2) ? &ebuf[(size_t)egn * 64 + kc * 32]
                : (kc < 4) ? &hbf[soff + (kc - 2) * 32]
                : (kc < 6) ? &hbf[roff + (kc - 4) * 32]
                :            &gpad[0];
        }
        bf16x8 a = *(const bf16x8*)&abase[q * 8];
#pragma unroll
        for (int i = 0; i < 4; ++i) {
          bf16x8 b = *(const bf16x8*)&w1p[(size_t)((kc * 8 + ntb1 + i) * 64 + lane) * 8];
          acc[i] = __builtin_amdgcn_mfma_f32_16x16x32_bf16(a, b, acc[i], 0, 0, 0);
        }
      }
#pragma unroll
      for (int i = 0; i < 4; ++i) {
        const int col = (ntb1 + i) * 16 + l15;
#pragma unroll
        for (int r4 = 0; r4 < 4; ++r4) {
          const int row = mr * 16 + q * 4 + r4;
          hid[cur ^ 1][row * 136 + col] = f2bf(gelu(acc[i][r4]));
        }
      }
      // prefetch indices for the tile after next
      const int t2 = tnext + G;
      if (t2 < NTILE) {
        s_nxt = snd[t2 * 32 + arow];
        r_nxt = rcv[t2 * 32 + arow];
      }
    }
    __syncthreads();
    cur ^= 1;
  }
  // ---- epilogue: last tile's easm
  ((uint4*)&ebuf[(size_t)(tile - G) * 2048])[tid] = ((const uint4*)easm[cur ^ 1])[tid];
}

// ---- MFMA node MLP + skip + LayerNorm; recv read fp32 + in-register f2bf.
// 32 nodes/block. K layout: [h 64][recv 64][g 16|pad] = 160 (KC=5); phase2 K=128.
__launch_bounds__(256)
__global__ void node_mfma(float* __restrict__ h, u16* __restrict__ hbf,
                          const float* __restrict__ recvb,
                          const u16* __restrict__ gpad,
                          const u16* __restrict__ w1p, const float* __restrict__ b1,
                          const u16* __restrict__ w2p, const float* __restrict__ b2,
                          const float* __restrict__ lns, const float* __restrict__ lnb) {
  __shared__ __align__(16) u16 hid[32 * 136];
  __shared__ __align__(16) float outs[32 * 68];

  const int tid = threadIdx.x;
  const int lane = tid & 63;
  const int w = tid >> 6;
  const int l15 = lane & 15;
  const int q = lane >> 4;
  const int mr = w & 1;
  const int ntb1 = (w >> 1) * 4;
  const int ntb2 = (w >> 1) * 2;
  const int arow = mr * 16 + l15;

  float bb1[4], bb2[2];
#pragma unroll
  for (int i = 0; i < 4; ++i) bb1[i] = b1[(ntb1 + i) * 16 + l15];
#pragma unroll
  for (int i = 0; i < 2; ++i) bb2[i] = b2[(ntb2 + i) * 16 + l15];

  const int nrow = tid >> 3;
  const int jc = (tid & 7) * 8;
  float sc8[8], bi8[8];
#pragma unroll
  for (int k = 0; k < 8; ++k) { sc8[k] = lns[jc + k]; bi8[k] = lnb[jc + k]; }

  const int NT = (NN + 31) / 32;
  for (int tile = blockIdx.x; tile < NT; tile += gridDim.x) {
    const int nbase = tile * 32;
    const int na = min(nbase + arow, NN - 1) * 64;   // clamped A-row offset

    // --- phase 1
    {
      f32x4 acc[4];
#pragma unroll
      for (int i = 0; i < 4; ++i) acc[i] = (f32x4){bb1[i], bb1[i], bb1[i], bb1[i]};
#pragma unroll
      for (int kc = 0; kc < 5; ++kc) {
        bf16x8 a;
        if (kc < 2) {
          a = *(const bf16x8*)&hbf[na + kc * 32 + q * 8];
        } else if (kc < 4) {
          const float* rp = &recvb[na + (kc - 2) * 32 + q * 8];
          union { u16 u[8]; bf16x8 v; } cv;
#pragma unroll
          for (int jj = 0; jj < 8; ++jj) cv.u[jj] = f2bf(rp[jj]);
          a = cv.v;
        } else {
          a = *(const bf16x8*)&gpad[q * 8];
        }
#pragma unroll
        for (int i = 0; i < 4; ++i) {
          bf16x8 b = *(const bf16x8*)&w1p[(size_t)((kc * 8 + ntb1 + i) * 64 + lane) * 8];
          acc[i] = __builtin_amdgcn_mfma_f32_16x16x32_bf16(a, b, acc[i], 0, 0, 0);
        }
      }
#pragma unroll
      for (int i = 0; i < 4; ++i) {
        const int col = (ntb1 + i) * 16 + l15;
#pragma unroll
        for (int r4 = 0; r4 < 4; ++r4) {
          const int row = mr * 16 + q * 4 + r4;
          hid[row * 136 + col] = f2bf(gelu(acc[i][r4]));
        }
      }
    }
    __syncthreads();
    // --- phase 2: upd = hid @ W2 + b2 -> outs (fp32 LDS)
    {
      f32x4 acc[2];
#pragma unroll
      for (int i = 0; i < 2; ++i) acc[i] = (f32x4){bb2[i], bb2[i], bb2[i], bb2[i]};
#pragma unroll
      for (int kc = 0; kc < 4; ++kc) {
        bf16x8 a = *(const bf16x8*)&hid[arow * 136 + kc * 32 + q * 8];
#pragma unroll
        for (int i = 0; i < 2; ++i) {
          bf16x8 b = *(const bf16x8*)&w2p[(size_t)((kc * 4 + ntb2 + i) * 64 + lane) * 8];
          acc[i] = __builtin_amdgcn_mfma_f32_16x16x32_bf16(a, b, acc[i], 0, 0, 0);
        }
      }
#pragma unroll
      for (int i = 0; i < 2; ++i) {
        const int col = (ntb2 + i) * 16 + l15;
#pragma unroll
        for (int r4 = 0; r4 < 4; ++r4) {
          const int row = mr * 16 + q * 4 + r4;
          outs[row * 68 + col] = acc[i][r4];
        }
      }
    }
    __syncthreads();
    // --- skip + LayerNorm: 8 threads per node row, 8 cols each
    {
      const int n = nbase + nrow;
      if (n < NN) {
        float x[8];
        float4 hv0 = *(const float4*)&h[n * 64 + jc];
        float4 hv1 = *(const float4*)&h[n * 64 + jc + 4];
        x[0] = hv0.x + outs[nrow * 68 + jc + 0];
        x[1] = hv0.y + outs[nrow * 68 + jc + 1];
        x[2] = hv0.z + outs[nrow * 68 + jc + 2];
        x[3] = hv0.w + outs[nrow * 68 + jc + 3];
        x[4] = hv1.x + outs[nrow * 68 + jc + 4];
        x[5] = hv1.y + outs[nrow * 68 + jc + 5];
        x[6] = hv1.z + outs[nrow * 68 + jc + 6];
        x[7] = hv1.w + outs[nrow * 68 + jc + 7];
        float s = 0.f, qq = 0.f;
#pragma unroll
        for (int k = 0; k < 8; ++k) { s += x[k]; qq += x[k] * x[k]; }
#pragma unroll
        for (int off = 1; off < 8; off <<= 1) {
          s += __shfl_xor(s, off);
          qq += __shfl_xor(qq, off);
        }
        float mean = s * (1.0f / 64.0f);
        float var = fmaxf(qq * (1.0f / 64.0f) - mean * mean, 0.0f);
        float rstd = rsqrtf(var + 1e-6f);
        float o[8];
        ushort4 ob0, ob1;
#pragma unroll
        for (int k = 0; k < 8; ++k) o[k] = (x[k] - mean) * rstd * sc8[k] + bi8[k];
        *(float4*)&h[n * 64 + jc]     = make_float4(o[0], o[1], o[2], o[3]);
        *(float4*)&h[n * 64 + jc + 4] = make_float4(o[4], o[5], o[6], o[7]);
        ob0.x = f2bf(o[0]); ob0.y = f2bf(o[1]); ob0.z = f2bf(o[2]); ob0.w = f2bf(o[3]);
        ob1.x = f2bf(o[4]); ob1.y = f2bf(o[5]); ob1.z = f2bf(o[6]); ob1.w = f2bf(o[7]);
        *(ushort4*)&hbf[n * 64 + jc]     = ob0;
        *(ushort4*)&hbf[n * 64 + jc + 4] = ob1;
      }
    }
    __syncthreads();   // protect hid/outs reuse next tile
  }
}

// Output dtype: float32 (reference returns fp32).
__global__ void decode_kernel(const float* __restrict__ h, const float* __restrict__ w,
                              const float* __restrict__ b, float* __restrict__ out) {
  int gid = blockIdx.x * blockDim.x + threadIdx.x;
  if (gid >= NN * INF) return;
  int n = gid / 7, f = gid % 7;
  float acc = b[f];
#pragma unroll
  for (int k = 0; k < LAT; ++k)
    acc = fmaf(h[n * 64 + k], w[k * 7 + f], acc);
  out[gid] = acc;
}

extern "C" void kernel_launch(void* const* d_in, const int* in_sizes, int n_in,
                              void* d_out, int out_size, void* d_ws, size_t ws_size,
                              hipStream_t stream) {
  const float* nodes = (const float*)d_in[0];
  const int* senders = (const int*)d_in[1];
  const int* recvrs  = (const int*)d_in[2];
  const float* g     = (const float*)d_in[3];
  const float* emb_w = (const float*)d_in[4];
  const float* emb_b = (const float*)d_in[5];
  const float* ew1f  = (const float*)d_in[6];
  const float* ew1r  = (const float*)d_in[7];
  const float* eb1   = (const float*)d_in[8];
  const float* ew2   = (const float*)d_in[9];
  const float* eb2   = (const float*)d_in[10];
  const float* nw1   = (const float*)d_in[11];
  const float* nb1   = (const float*)d_in[12];
  const float* nw2   = (const float*)d_in[13];
  const float* nb2   = (const float*)d_in[14];
  const float* lns   = (const float*)d_in[15];
  const float* lnb   = (const float*)d_in[16];
  const float* dw    = (const float*)d_in[17];
  const float* db    = (const float*)d_in[18];

  char* cur = (char*)d_ws;
  float* h      = (float*)cur;  cur += (size_t)NN * LAT * 4;        // 12.8 MB
  float* recvb  = (float*)cur;  cur += (size_t)NN * LAT * 4;        // 12.8 MB
  u16*   ebuf   = (u16*)cur;    cur += (size_t)NE * LAT * 2;        // 102.4 MB
  u16*   hbf    = (u16*)cur;    cur += (size_t)NN * LAT * 2;        // 6.4 MB
  u16*   ew1p[3]; for (int t = 0; t < 3; ++t) { ew1p[t] = (u16*)cur; cur += 7 * 8 * 64 * 8 * 2; }
  u16*   ew2p[3]; for (int t = 0; t < 3; ++t) { ew2p[t] = (u16*)cur; cur += 4 * 4 * 64 * 8 * 2; }
  u16*   nw1p[3]; for (int t = 0; t < 3; ++t) { nw1p[t] = (u16*)cur; cur += 5 * 8 * 64 * 8 * 2; }
  u16*   nw2p[3]; for (int t = 0; t < 3; ++t) { nw2p[t] = (u16*)cur; cur += 4 * 4 * 64 * 8 * 2; }
  u16*   gpad   = (u16*)cur;    cur += 64;

  // single consolidated pre-pack dispatch (13 jobs)
  PackJobs J;
  J.src[0] = ew1f;                       J.dst[0] = ew1p[0]; J.K[0] = 144; J.N[0] = 128; J.KC[0] = 5;
  J.src[1] = ew1r;                       J.dst[1] = ew1p[1]; J.K[1] = 208; J.N[1] = 128; J.KC[1] = 7;
  J.src[2] = ew1r + (size_t)208 * 128;   J.dst[2] = ew1p[2]; J.K[2] = 208; J.N[2] = 128; J.KC[2] = 7;
  for (int t = 0; t < 3; ++t) {
    J.src[3 + t] = ew2 + (size_t)t * 128 * 64;  J.dst[3 + t] = ew2p[t]; J.K[3 + t] = 128; J.N[3 + t] = 64; J.KC[3 + t] = 4;
    J.src[6 + t] = nw1 + (size_t)t * 144 * 128; J.dst[6 + t] = nw1p[t]; J.K[6 + t] = 144; J.N[6 + t] = 128; J.KC[6 + t] = 5;
    J.src[9 + t] = nw2 + (size_t)t * 128 * 64;  J.dst[9 + t] = nw2p[t]; J.K[9 + t] = 128; J.N[9 + t] = 64; J.KC[9 + t] = 4;
  }
  J.src[12] = g; J.dst[12] = gpad; J.K[12] = 0; J.N[12] = 0; J.KC[12] = 0;
  pack_all<<<dim3(16, 13), 256, 0, stream>>>(J);

  embed_kernel<<<(NN * LAT + 255) / 256, 256, 0, stream>>>(nodes, emb_w, emb_b, h, hbf);

  for (int t = 0; t < 3; ++t) {
    hipMemsetAsync(recvb, 0, (size_t)NN * LAT * 4, stream);
    if (t == 0)
      edge_mfma<5, true><<<2048, 256, 0, stream>>>(hbf, ebuf, recvb,
          senders, recvrs, gpad, ew1p[0], eb1, ew2p[0], eb2);
    else
      edge_mfma<7, false><<<2048, 256, 0, stream>>>(hbf, ebuf, recvb,
          senders, recvrs, gpad, ew1p[t], eb1 + t * 128, ew2p[t], eb2 + t * 64);
    node_mfma<<<1563, 256, 0, stream>>>(h, hbf, recvb, gpad,
        nw1p[t], nb1 + t * 128, nw2p[t], nb2 + t * 64,
        lns + t * 64, lnb + t * 64);
  }

  decode_kernel<<<(NN * INF + 255) / 256, 256, 0, stream>>>(h, dw, db, (float*)d_out);
}

// Round 16
// 748.484 us; speedup vs baseline: 1.2203x; 1.2203x over previous
//
#include <hip/hip_runtime.h>

#define NN 50000
#define NE 800000
#define INF 7
#define GD 16
#define LAT 64
#define HID 128

typedef unsigned short u16;
typedef __attribute__((ext_vector_type(8))) __bf16 bf16x8;
typedef __attribute__((ext_vector_type(4))) float f32x4;

__device__ __forceinline__ float bf2f(u16 u) {
  union { unsigned int i; float f; } v; v.i = ((unsigned int)u) << 16; return v.f;
}
__device__ __forceinline__ u16 f2bf(float f) {
  union { float f; unsigned int i; } v; v.f = f;
  unsigned int x = v.i;
  return (u16)((x + 0x7fffu + ((x >> 16) & 1u)) >> 16);
}
// jax.nn.gelu approximate (tanh form) as x*sigmoid(2z) with v_rcp (r11-verified).
__device__ __forceinline__ float gelu(float x) {
  float u = x * x;
  float p = fmaf(0.044715f * u, x, x);
  float e = __expf(-1.5957691216057308f * p);
  return x * __builtin_amdgcn_rcpf(e + 1.0f);
}

// ---- consolidated weight pre-pack: 13 jobs in one dispatch.
struct PackJobs {
  const float* src[13];
  u16* dst[13];
  int K[13];
  int N[13];
  int KC[13];
};

__global__ void pack_all(PackJobs J) {
  const int j = blockIdx.y;
  const int KC = J.KC[j];
  const float* W = J.src[j];
  u16* out = J.dst[j];
  int t = blockIdx.x * blockDim.x + threadIdx.x;
  if (KC == 0) {            // gpad job
    if (t < 32) out[t] = (t < GD) ? f2bf(W[t]) : (u16)0;
    return;
  }
  const int K = J.K[j], N = J.N[j];
  const int NT = N >> 4;
  if (t >= KC * NT * 64) return;
  int l = t & 63;
  int nt = (t >> 6) % NT;
  int kc = t / (64 * NT);
  int n = nt * 16 + (l & 15);
  int kbase = kc * 32 + (l >> 4) * 8;
  ushort4 lo, hi;
  u16 v[8];
#pragma unroll
  for (int jj = 0; jj < 8; ++jj) {
    int k = kbase + jj;
    v[jj] = (k < K) ? f2bf(W[k * N + n]) : (u16)0;
  }
  lo.x = v[0]; lo.y = v[1]; lo.z = v[2]; lo.w = v[3];
  hi.x = v[4]; hi.y = v[5]; hi.z = v[6]; hi.w = v[7];
  ushort4* dst = (ushort4*)&out[(size_t)t * 8];
  dst[0] = lo; dst[1] = hi;
}

__global__ void embed_kernel(const float* __restrict__ nodes, const float* __restrict__ w,
                             const float* __restrict__ b, float* __restrict__ h,
                             u16* __restrict__ hbf) {
  int gid = blockIdx.x * blockDim.x + threadIdx.x;
  if (gid >= NN * LAT) return;
  int n = gid >> 6, j = gid & 63;
  float acc = b[j];
#pragma unroll
  for (int k = 0; k < INF; ++k)
    acc = fmaf(nodes[n * INF + k], w[k * LAT + j], acc);
  h[gid] = acc;
  hbf[gid] = f2bf(acc);
}

// ---- MFMA edge MLP (r13 structure -- the empirical optimum of this design
// space). 32 edges/block, two barriers per tile (implicit cross-phase wave
// overlap does the pipelining; explicit SW pipelining regressed -- r15).
// NO weight LDS staging (quarantined: r8/r9/r10). Unsorted edges, plain
// atomics (receiver sort regressed -- r14).
// K layout FIRST: [s 64][r 64][g 16|pad] = 160 (KC=5)
//          else : [e 64][s 64][r 64][g 16|pad] = 224 (KC=7)
template <int KC, bool FIRST>
__launch_bounds__(256)
__global__ void edge_mfma(const u16* __restrict__ hbf, u16* __restrict__ ebuf,
                          float* __restrict__ recvbuf,
                          const int* __restrict__ snd, const int* __restrict__ rcv,
                          const u16* __restrict__ gpad,
                          const u16* __restrict__ w1p, const float* __restrict__ b1,
                          const u16* __restrict__ w2p, const float* __restrict__ b2) {
  __shared__ __align__(16) u16 hid[32 * 136];
  __shared__ __align__(16) u16 easm[32 * 64];
  __shared__ int rcvs[32];

  const int tid = threadIdx.x;
  const int lane = tid & 63;
  const int w = tid >> 6;
  const int l15 = lane & 15;
  const int q = lane >> 4;
  const int mr = w & 1;              // row-tile (16 rows) for both phases
  const int ntb1 = (w >> 1) * 4;     // phase-1 col-tiles (4 of 8)
  const int ntb2 = (w >> 1) * 2;     // phase-2 col-tiles (2 of 4)
  const int arow = mr * 16 + l15;
  const int NTILE = NE / 32;

  float bb1[4], bb2[2];
#pragma unroll
  for (int i = 0; i < 4; ++i) bb1[i] = b1[(ntb1 + i) * 16 + l15];
#pragma unroll
  for (int i = 0; i < 2; ++i) bb2[i] = b2[(ntb2 + i) * 16 + l15];

  // prefetch indices for the first tile
  int s_cur = 0, r_cur = 0;
  if (blockIdx.x < NTILE) {
    const int eg0 = blockIdx.x * 32 + arow;
    s_cur = snd[eg0];
    r_cur = rcv[eg0];
  }

  for (int tile = blockIdx.x; tile < NTILE; tile += gridDim.x) {
    const int ebase = tile * 32;
    const int eg = ebase + arow;
    const int soff = s_cur * 64;
    const int roff = r_cur * 64;
    if (tid < 32) rcvs[tid] = rcv[ebase + tid];

    // prefetch next tile's indices (consumed next iteration)
    {
      int tn = tile + gridDim.x;
      if (tn < NTILE) {
        const int egn = tn * 32 + arow;
        s_cur = snd[egn];
        r_cur = rcv[egn];
      }
    }

    // --- phase 1: hid = gelu(in @ W1 + b1)   [32 x 128]
    {
      f32x4 acc[4];
#pragma unroll
      for (int i = 0; i < 4; ++i) acc[i] = (f32x4){bb1[i], bb1[i], bb1[i], bb1[i]};
#pragma unroll
      for (int kc = 0; kc < KC; ++kc) {
        const u16* abase;
        if (FIRST) {
          abase = (kc < 2) ? &hbf[soff + kc * 32]
                : (kc < 4) ? &hbf[roff + (kc - 2) * 32]
                :            &gpad[0];
        } else {
          abase = (kc < 2) ? &ebuf[(size_t)eg * 64 + kc * 32]
                : (kc < 4) ? &hbf[soff + (kc - 2) * 32]
                : (kc < 6) ? &hbf[roff + (kc - 4) * 32]
                :            &gpad[0];
        }
        bf16x8 a = *(const bf16x8*)&abase[q * 8];
#pragma unroll
        for (int i = 0; i < 4; ++i) {
          bf16x8 b = *(const bf16x8*)&w1p[(size_t)((kc * 8 + ntb1 + i) * 64 + lane) * 8];
          acc[i] = __builtin_amdgcn_mfma_f32_16x16x32_bf16(a, b, acc[i], 0, 0, 0);
        }
      }
#pragma unroll
      for (int i = 0; i < 4; ++i) {
        const int col = (ntb1 + i) * 16 + l15;
#pragma unroll
        for (int r4 = 0; r4 < 4; ++r4) {
          const int row = mr * 16 + q * 4 + r4;
          hid[row * 136 + col] = f2bf(gelu(acc[i][r4]));
        }
      }
    }
    __syncthreads();
    // --- phase 2: out = hid @ W2 + b2   [32 x 64]; easm + atomics
    {
      f32x4 acc[2];
#pragma unroll
      for (int i = 0; i < 2; ++i) acc[i] = (f32x4){bb2[i], bb2[i], bb2[i], bb2[i]};
#pragma unroll
      for (int kc = 0; kc < 4; ++kc) {
        bf16x8 a = *(const bf16x8*)&hid[arow * 136 + kc * 32 + q * 8];
#pragma unroll
        for (int i = 0; i < 2; ++i) {
          bf16x8 b = *(const bf16x8*)&w2p[(size_t)((kc * 4 + ntb2 + i) * 64 + lane) * 8];
          acc[i] = __builtin_amdgcn_mfma_f32_16x16x32_bf16(a, b, acc[i], 0, 0, 0);
        }
      }
#pragma unroll
      for (int i = 0; i < 2; ++i) {
        const int col = (ntb2 + i) * 16 + l15;
#pragma unroll
        for (int r4 = 0; r4 < 4; ++r4) {
          const int row = mr * 16 + q * 4 + r4;
          const float v = acc[i][r4];
          easm[row * 64 + col] = f2bf(v);
          atomicAdd(&recvbuf[(size_t)rcvs[row] * 64 + col], v);
        }
      }
    }
    __syncthreads();
    // --- coalesced e_out write: 256 threads x 16B = 32 rows x 128B
    ((uint4*)&ebuf[(size_t)ebase * 64])[tid] = ((const uint4*)easm)[tid];
  }
}

// ---- MFMA node MLP + skip + LayerNorm; recv read fp32 + in-register f2bf.
// 32 nodes/block. K layout: [h 64][recv 64][g 16|pad] = 160 (KC=5); phase2 K=128.
__launch_bounds__(256)
__global__ void node_mfma(float* __restrict__ h, u16* __restrict__ hbf,
                          const float* __restrict__ recvb,
                          const u16* __restrict__ gpad,
                          const u16* __restrict__ w1p, const float* __restrict__ b1,
                          const u16* __restrict__ w2p, const float* __restrict__ b2,
                          const float* __restrict__ lns, const float* __restrict__ lnb) {
  __shared__ __align__(16) u16 hid[32 * 136];
  __shared__ __align__(16) float outs[32 * 68];

  const int tid = threadIdx.x;
  const int lane = tid & 63;
  const int w = tid >> 6;
  const int l15 = lane & 15;
  const int q = lane >> 4;
  const int mr = w & 1;
  const int ntb1 = (w >> 1) * 4;
  const int ntb2 = (w >> 1) * 2;
  const int arow = mr * 16 + l15;

  float bb1[4], bb2[2];
#pragma unroll
  for (int i = 0; i < 4; ++i) bb1[i] = b1[(ntb1 + i) * 16 + l15];
#pragma unroll
  for (int i = 0; i < 2; ++i) bb2[i] = b2[(ntb2 + i) * 16 + l15];

  const int nrow = tid >> 3;
  const int jc = (tid & 7) * 8;
  float sc8[8], bi8[8];
#pragma unroll
  for (int k = 0; k < 8; ++k) { sc8[k] = lns[jc + k]; bi8[k] = lnb[jc + k]; }

  const int NT = (NN + 31) / 32;
  for (int tile = blockIdx.x; tile < NT; tile += gridDim.x) {
    const int nbase = tile * 32;
    const int na = min(nbase + arow, NN - 1) * 64;   // clamped A-row offset

    // --- phase 1
    {
      f32x4 acc[4];
#pragma unroll
      for (int i = 0; i < 4; ++i) acc[i] = (f32x4){bb1[i], bb1[i], bb1[i], bb1[i]};
#pragma unroll
      for (int kc = 0; kc < 5; ++kc) {
        bf16x8 a;
        if (kc < 2) {
          a = *(const bf16x8*)&hbf[na + kc * 32 + q * 8];
        } else if (kc < 4) {
          const float* rp = &recvb[na + (kc - 2) * 32 + q * 8];
          union { u16 u[8]; bf16x8 v; } cv;
#pragma unroll
          for (int jj = 0; jj < 8; ++jj) cv.u[jj] = f2bf(rp[jj]);
          a = cv.v;
        } else {
          a = *(const bf16x8*)&gpad[q * 8];
        }
#pragma unroll
        for (int i = 0; i < 4; ++i) {
          bf16x8 b = *(const bf16x8*)&w1p[(size_t)((kc * 8 + ntb1 + i) * 64 + lane) * 8];
          acc[i] = __builtin_amdgcn_mfma_f32_16x16x32_bf16(a, b, acc[i], 0, 0, 0);
        }
      }
#pragma unroll
      for (int i = 0; i < 4; ++i) {
        const int col = (ntb1 + i) * 16 + l15;
#pragma unroll
        for (int r4 = 0; r4 < 4; ++r4) {
          const int row = mr * 16 + q * 4 + r4;
          hid[row * 136 + col] = f2bf(gelu(acc[i][r4]));
        }
      }
    }
    __syncthreads();
    // --- phase 2: upd = hid @ W2 + b2 -> outs (fp32 LDS)
    {
      f32x4 acc[2];
#pragma unroll
      for (int i = 0; i < 2; ++i) acc[i] = (f32x4){bb2[i], bb2[i], bb2[i], bb2[i]};
#pragma unroll
      for (int kc = 0; kc < 4; ++kc) {
        bf16x8 a = *(const bf16x8*)&hid[arow * 136 + kc * 32 + q * 8];
#pragma unroll
        for (int i = 0; i < 2; ++i) {
          bf16x8 b = *(const bf16x8*)&w2p[(size_t)((kc * 4 + ntb2 + i) * 64 + lane) * 8];
          acc[i] = __builtin_amdgcn_mfma_f32_16x16x32_bf16(a, b, acc[i], 0, 0, 0);
        }
      }
#pragma unroll
      for (int i = 0; i < 2; ++i) {
        const int col = (ntb2 + i) * 16 + l15;
#pragma unroll
        for (int r4 = 0; r4 < 4; ++r4) {
          const int row = mr * 16 + q * 4 + r4;
          outs[row * 68 + col] = acc[i][r4];
        }
      }
    }
    __syncthreads();
    // --- skip + LayerNorm: 8 threads per node row, 8 cols each
    {
      const int n = nbase + nrow;
      if (n < NN) {
        float x[8];
        float4 hv0 = *(const float4*)&h[n * 64 + jc];
        float4 hv1 = *(const float4*)&h[n * 64 + jc + 4];
        x[0] = hv0.x + outs[nrow * 68 + jc + 0];
        x[1] = hv0.y + outs[nrow * 68 + jc + 1];
        x[2] = hv0.z + outs[nrow * 68 + jc + 2];
        x[3] = hv0.w + outs[nrow * 68 + jc + 3];
        x[4] = hv1.x + outs[nrow * 68 + jc + 4];
        x[5] = hv1.y + outs[nrow * 68 + jc + 5];
        x[6] = hv1.z + outs[nrow * 68 + jc + 6];
        x[7] = hv1.w + outs[nrow * 68 + jc + 7];
        float s = 0.f, qq = 0.f;
#pragma unroll
        for (int k = 0; k < 8; ++k) { s += x[k]; qq += x[k] * x[k]; }
#pragma unroll
        for (int off = 1; off < 8; off <<= 1) {
          s += __shfl_xor(s, off);
          qq += __shfl_xor(qq, off);
        }
        float mean = s * (1.0f / 64.0f);
        float var = fmaxf(qq * (1.0f / 64.0f) - mean * mean, 0.0f);
        float rstd = rsqrtf(var + 1e-6f);
        float o[8];
        ushort4 ob0, ob1;
#pragma unroll
        for (int k = 0; k < 8; ++k) o[k] = (x[k] - mean) * rstd * sc8[k] + bi8[k];
        *(float4*)&h[n * 64 + jc]     = make_float4(o[0], o[1], o[2], o[3]);
        *(float4*)&h[n * 64 + jc + 4] = make_float4(o[4], o[5], o[6], o[7]);
        ob0.x = f2bf(o[0]); ob0.y = f2bf(o[1]); ob0.z = f2bf(o[2]); ob0.w = f2bf(o[3]);
        ob1.x = f2bf(o[4]); ob1.y = f2bf(o[5]); ob1.z = f2bf(o[6]); ob1.w = f2bf(o[7]);
        *(ushort4*)&hbf[n * 64 + jc]     = ob0;
        *(ushort4*)&hbf[n * 64 + jc + 4] = ob1;
      }
    }
    __syncthreads();   // protect hid/outs reuse next tile
  }
}

// Output dtype: float32 (reference returns fp32).
__global__ void decode_kernel(const float* __restrict__ h, const float* __restrict__ w,
                              const float* __restrict__ b, float* __restrict__ out) {
  int gid = blockIdx.x * blockDim.x + threadIdx.x;
  if (gid >= NN * INF) return;
  int n = gid / 7, f = gid % 7;
  float acc = b[f];
#pragma unroll
  for (int k = 0; k < LAT; ++k)
    acc = fmaf(h[n * 64 + k], w[k * 7 + f], acc);
  out[gid] = acc;
}

extern "C" void kernel_launch(void* const* d_in, const int* in_sizes, int n_in,
                              void* d_out, int out_size, void* d_ws, size_t ws_size,
                              hipStream_t stream) {
  const float* nodes = (const float*)d_in[0];
  const int* senders = (const int*)d_in[1];
  const int* recvrs  = (const int*)d_in[2];
  const float* g     = (const float*)d_in[3];
  const float* emb_w = (const float*)d_in[4];
  const float* emb_b = (const float*)d_in[5];
  const float* ew1f  = (const float*)d_in[6];
  const float* ew1r  = (const float*)d_in[7];
  const float* eb1   = (const float*)d_in[8];
  const float* ew2   = (const float*)d_in[9];
  const float* eb2   = (const float*)d_in[10];
  const float* nw1   = (const float*)d_in[11];
  const float* nb1   = (const float*)d_in[12];
  const float* nw2   = (const float*)d_in[13];
  const float* nb2   = (const float*)d_in[14];
  const float* lns   = (const float*)d_in[15];
  const float* lnb   = (const float*)d_in[16];
  const float* dw    = (const float*)d_in[17];
  const float* db    = (const float*)d_in[18];

  char* cur = (char*)d_ws;
  float* h      = (float*)cur;  cur += (size_t)NN * LAT * 4;        // 12.8 MB
  float* recvb  = (float*)cur;  cur += (size_t)NN * LAT * 4;        // 12.8 MB
  u16*   ebuf   = (u16*)cur;    cur += (size_t)NE * LAT * 2;        // 102.4 MB
  u16*   hbf    = (u16*)cur;    cur += (size_t)NN * LAT * 2;        // 6.4 MB
  u16*   ew1p[3]; for (int t = 0; t < 3; ++t) { ew1p[t] = (u16*)cur; cur += 7 * 8 * 64 * 8 * 2; }
  u16*   ew2p[3]; for (int t = 0; t < 3; ++t) { ew2p[t] = (u16*)cur; cur += 4 * 4 * 64 * 8 * 2; }
  u16*   nw1p[3]; for (int t = 0; t < 3; ++t) { nw1p[t] = (u16*)cur; cur += 5 * 8 * 64 * 8 * 2; }
  u16*   nw2p[3]; for (int t = 0; t < 3; ++t) { nw2p[t] = (u16*)cur; cur += 4 * 4 * 64 * 8 * 2; }
  u16*   gpad   = (u16*)cur;    cur += 64;

  // single consolidated pre-pack dispatch (13 jobs)
  PackJobs J;
  J.src[0] = ew1f;                       J.dst[0] = ew1p[0]; J.K[0] = 144; J.N[0] = 128; J.KC[0] = 5;
  J.src[1] = ew1r;                       J.dst[1] = ew1p[1]; J.K[1] = 208; J.N[1] = 128; J.KC[1] = 7;
  J.src[2] = ew1r + (size_t)208 * 128;   J.dst[2] = ew1p[2]; J.K[2] = 208; J.N[2] = 128; J.KC[2] = 7;
  for (int t = 0; t < 3; ++t) {
    J.src[3 + t] = ew2 + (size_t)t * 128 * 64;  J.dst[3 + t] = ew2p[t]; J.K[3 + t] = 128; J.N[3 + t] = 64; J.KC[3 + t] = 4;
    J.src[6 + t] = nw1 + (size_t)t * 144 * 128; J.dst[6 + t] = nw1p[t]; J.K[6 + t] = 144; J.N[6 + t] = 128; J.KC[6 + t] = 5;
    J.src[9 + t] = nw2 + (size_t)t * 128 * 64;  J.dst[9 + t] = nw2p[t]; J.K[9 + t] = 128; J.N[9 + t] = 64; J.KC[9 + t] = 4;
  }
  J.src[12] = g; J.dst[12] = gpad; J.K[12] = 0; J.N[12] = 0; J.KC[12] = 0;
  pack_all<<<dim3(16, 13), 256, 0, stream>>>(J);

  embed_kernel<<<(NN * LAT + 255) / 256, 256, 0, stream>>>(nodes, emb_w, emb_b, h, hbf);

  for (int t = 0; t < 3; ++t) {
    hipMemsetAsync(recvb, 0, (size_t)NN * LAT * 4, stream);
    if (t == 0)
      edge_mfma<5, true><<<2048, 256, 0, stream>>>(hbf, ebuf, recvb,
          senders, recvrs, gpad, ew1p[0], eb1, ew2p[0], eb2);
    else
      edge_mfma<7, false><<<2048, 256, 0, stream>>>(hbf, ebuf, recvb,
          senders, recvrs, gpad, ew1p[t], eb1 + t * 128, ew2p[t], eb2 + t * 64);
    node_mfma<<<1563, 256, 0, stream>>>(h, hbf, recvb, gpad,
        nw1p[t], nb1 + t * 128, nw2p[t], nb2 + t * 64,
        lns + t * 64, lnb + t * 64);
  }

  decode_kernel<<<(NN * INF + 255) / 256, 256, 0, stream>>>(h, dw, db, (float*)d_out);
}